// Round 1
// baseline (271.353 us; speedup 1.0000x reference)
//
#include <hip/hip_runtime.h>
#include <hip/hip_bf16.h>

#define NGROUPS 8   // L=2 labels * S=4 sessions
#define DIM 128
// workspace layout (floats): [0,1024) sums[8][128], [1024,2048) wsums[8][128], [2048,2056) counts[8]
#define WS_FLOATS 2056

__global__ __launch_bounds__(256)
void csca_accum_kernel(const float4* __restrict__ feat4,
                       const int* __restrict__ labels,
                       const int* __restrict__ sessions,
                       float* __restrict__ gws, int B) {
    __shared__ float s_all[WS_FLOATS];
    for (int i = threadIdx.x; i < WS_FLOATS; i += 256) s_all[i] = 0.0f;
    __syncthreads();

    const int lane = threadIdx.x & 63;
    const int waveInBlock = threadIdx.x >> 6;     // 0..3
    const int sub = lane & 31;                    // dim slice owner within half-wave
    const int half = lane >> 5;                   // 0/1: which row of the pair
    const int halfId = blockIdx.x * 8 + waveInBlock * 2 + half;
    const int stride = gridDim.x * 8;             // total half-waves

    float sa[NGROUPS][4];
    float wa[NGROUPS][4];
    float cnt[NGROUPS];
#pragma unroll
    for (int g = 0; g < NGROUPS; ++g) {
        cnt[g] = 0.0f;
#pragma unroll
        for (int k = 0; k < 4; ++k) { sa[g][k] = 0.0f; wa[g][k] = 0.0f; }
    }

    for (int row = halfId; row < B; row += stride) {
        float4 v = feat4[row * 32 + sub];
        int g = labels[row] * 4 + sessions[row];
        float ss = v.x * v.x + v.y * v.y + v.z * v.z + v.w * v.w;
        // reduce within the 32-lane half (masks 1..16 stay inside each half)
        ss += __shfl_xor(ss, 1);
        ss += __shfl_xor(ss, 2);
        ss += __shfl_xor(ss, 4);
        ss += __shfl_xor(ss, 8);
        ss += __shfl_xor(ss, 16);
        float rn = 1.0f / fmaxf(sqrtf(ss), 1e-8f);
#pragma unroll
        for (int gg = 0; gg < NGROUPS; ++gg) {
            float m = (gg == g) ? 1.0f : 0.0f;
            float wm = m * rn;
            cnt[gg] += m;
            sa[gg][0] = fmaf(m, v.x, sa[gg][0]);
            sa[gg][1] = fmaf(m, v.y, sa[gg][1]);
            sa[gg][2] = fmaf(m, v.z, sa[gg][2]);
            sa[gg][3] = fmaf(m, v.w, sa[gg][3]);
            wa[gg][0] = fmaf(wm, v.x, wa[gg][0]);
            wa[gg][1] = fmaf(wm, v.y, wa[gg][1]);
            wa[gg][2] = fmaf(wm, v.z, wa[gg][2]);
            wa[gg][3] = fmaf(wm, v.w, wa[gg][3]);
        }
    }

    // fold the two halves of the wave (lane l += lane l^32); cnt becomes wave-total
#pragma unroll
    for (int g = 0; g < NGROUPS; ++g) {
#pragma unroll
        for (int k = 0; k < 4; ++k) {
            sa[g][k] += __shfl_xor(sa[g][k], 32);
            wa[g][k] += __shfl_xor(wa[g][k], 32);
        }
        cnt[g] += __shfl_xor(cnt[g], 32);
    }

    // per-block LDS reduction
    if (lane < 32) {
#pragma unroll
        for (int g = 0; g < NGROUPS; ++g) {
#pragma unroll
            for (int k = 0; k < 4; ++k) {
                atomicAdd(&s_all[g * DIM + sub * 4 + k], sa[g][k]);
                atomicAdd(&s_all[1024 + g * DIM + sub * 4 + k], wa[g][k]);
            }
        }
    }
    if (lane == 0) {
#pragma unroll
        for (int g = 0; g < NGROUPS; ++g) atomicAdd(&s_all[2048 + g], cnt[g]);
    }
    __syncthreads();

    // one global atomic per shared element per block
    for (int i = threadIdx.x; i < WS_FLOATS; i += 256) atomicAdd(&gws[i], s_all[i]);
}

__global__ __launch_bounds__(64)
void csca_finalize_kernel(const float* __restrict__ gws, float* __restrict__ out, float invB) {
    const int lane = threadIdx.x;  // 0..63, single wave
    const float* sums  = gws;
    const float* wsums = gws + 1024;
    const float* cnts  = gws + 2048;
    __shared__ float c_lds[NGROUPS][DIM];
    float cnorm2[NGROUPS];
    float cos_sum = 0.0f;

#pragma unroll
    for (int g = 0; g < NGROUPS; ++g) {
        float invc = 1.0f / cnts[g];
        float c0 = sums[g * DIM + lane] * invc;
        float c1 = sums[g * DIM + 64 + lane] * invc;
        c_lds[g][lane] = c0;
        c_lds[g][64 + lane] = c1;
        float w0 = wsums[g * DIM + lane];
        float w1 = wsums[g * DIM + 64 + lane];
        float pcc = c0 * c0 + c1 * c1;
        float pwc = w0 * c0 + w1 * c1;
#pragma unroll
        for (int m = 1; m < 64; m <<= 1) {
            pcc += __shfl_xor(pcc, m);
            pwc += __shfl_xor(pwc, m);
        }
        cnorm2[g] = pcc;
        cos_sum += pwc / fmaxf(sqrtf(pcc), 1e-8f);
    }
    float center_loss = 1.0f - cos_sum * invB;
    __syncthreads();

    float align = 0.0f;
#pragma unroll
    for (int y = 0; y < 2; ++y) {
        float p0 = 0.0f, p1 = 0.0f;
#pragma unroll
        for (int s = 0; s < 4; ++s) {
            p0 += c_lds[4 * y + s][lane];
            p1 += c_lds[4 * y + s][64 + lane];
        }
        p0 *= 0.25f; p1 *= 0.25f;
        float ppp = p0 * p0 + p1 * p1;
#pragma unroll
        for (int m = 1; m < 64; m <<= 1) ppp += __shfl_xor(ppp, m);
        float pn = fmaxf(sqrtf(ppp), 1e-8f);
        float pc = 0.0f;
#pragma unroll
        for (int s = 0; s < 4; ++s) {
            float d = c_lds[4 * y + s][lane] * p0 + c_lds[4 * y + s][64 + lane] * p1;
#pragma unroll
            for (int m = 1; m < 64; m <<= 1) d += __shfl_xor(d, m);
            float cs = d / (fmaxf(sqrtf(cnorm2[4 * y + s]), 1e-8f) * pn);
            pc += 1.0f - cs;
        }
        align = (align + pc) * 0.25f;  // running /S division, faithful to reference
    }

    if (lane == 0) {
        out[0] = center_loss + align;
        out[1] = center_loss;
        out[2] = align;
    }
}

extern "C" void kernel_launch(void* const* d_in, const int* in_sizes, int n_in,
                              void* d_out, int out_size, void* d_ws, size_t ws_size,
                              hipStream_t stream) {
    const float* feat = (const float*)d_in[0];
    const int* labels = (const int*)d_in[1];
    const int* sessions = (const int*)d_in[2];
    const int B = in_sizes[1];          // 1048576 (features are B x 128)
    float* gws = (float*)d_ws;

    hipMemsetAsync(gws, 0, WS_FLOATS * sizeof(float), stream);

    csca_accum_kernel<<<1024, 256, 0, stream>>>((const float4*)feat, labels, sessions, gws, B);
    csca_finalize_kernel<<<1, 64, 0, stream>>>(gws, (float*)d_out, 1.0f / (float)B);
}

// Round 2
// 244.645 us; speedup vs baseline: 1.1092x; 1.1092x over previous
//
#include <hip/hip_runtime.h>
#include <hip/hip_bf16.h>

#define NGROUPS 8   // L=2 labels * S=4 sessions
#define DIM 128
// per-replica layout (floats): [0,1024) sums[8][128], [1024,2048) wsums[8][128], [2048,2056) counts[8]
#define WS_FLOATS 2056
#define NREP 16     // global atomic replicas to cut same-address chains

// accumulate one (wave-uniform) row's contribution; G is an SGPR int
#define ACCUM_ROW(G, V, RN)                                              \
    {                                                                    \
        _Pragma("unroll")                                                \
        for (int gg = 0; gg < NGROUPS; ++gg) {                           \
            if ((G) == gg) {                                             \
                scnt[gg] += 1;                                           \
                sax[gg] += (V).x;                                        \
                say[gg] += (V).y;                                        \
                wax[gg] = fmaf((RN), (V).x, wax[gg]);                    \
                way[gg] = fmaf((RN), (V).y, way[gg]);                    \
            }                                                            \
        }                                                                \
    }

__global__ __launch_bounds__(256, 6)
void csca_accum_kernel(const float2* __restrict__ feat2,
                       const int* __restrict__ labels,
                       const int* __restrict__ sessions,
                       float* __restrict__ gws, int B) {
    __shared__ float s_all[WS_FLOATS];
    for (int i = threadIdx.x; i < WS_FLOATS; i += 256) s_all[i] = 0.0f;
    __syncthreads();

    const int lane = threadIdx.x & 63;
    const int wid = blockIdx.x * 4 + (threadIdx.x >> 6);  // global wave id
    const int NW = gridDim.x * 4;                         // total waves

    float sax[NGROUPS], say[NGROUPS], wax[NGROUPS], way[NGROUPS];
    int scnt[NGROUPS];
#pragma unroll
    for (int g = 0; g < NGROUPS; ++g) {
        sax[g] = 0.0f; say[g] = 0.0f; wax[g] = 0.0f; way[g] = 0.0f; scnt[g] = 0;
    }

    const int fullIters = B / (NW * 4);
    for (int it = 0; it < fullIters; ++it) {
        const int r0 = (it * NW + wid) * 4;
        // 4 independent row loads (512B per wave each, fully coalesced)
        float2 v0 = feat2[(size_t)(r0 + 0) * 64 + lane];
        float2 v1 = feat2[(size_t)(r0 + 1) * 64 + lane];
        float2 v2 = feat2[(size_t)(r0 + 2) * 64 + lane];
        float2 v3 = feat2[(size_t)(r0 + 3) * 64 + lane];
        // wave-uniform group ids -> SGPRs
        int g0 = __builtin_amdgcn_readfirstlane(labels[r0 + 0] * 4 + sessions[r0 + 0]);
        int g1 = __builtin_amdgcn_readfirstlane(labels[r0 + 1] * 4 + sessions[r0 + 1]);
        int g2 = __builtin_amdgcn_readfirstlane(labels[r0 + 2] * 4 + sessions[r0 + 2]);
        int g3 = __builtin_amdgcn_readfirstlane(labels[r0 + 3] * 4 + sessions[r0 + 3]);

        float s0 = fmaf(v0.x, v0.x, v0.y * v0.y);
        float s1 = fmaf(v1.x, v1.x, v1.y * v1.y);
        float s2 = fmaf(v2.x, v2.x, v2.y * v2.y);
        float s3 = fmaf(v3.x, v3.x, v3.y * v3.y);
        // 4 interleaved 64-lane reduces: DS latencies overlap
#pragma unroll
        for (int m = 1; m < 64; m <<= 1) {
            s0 += __shfl_xor(s0, m);
            s1 += __shfl_xor(s1, m);
            s2 += __shfl_xor(s2, m);
            s3 += __shfl_xor(s3, m);
        }
        float rn0 = 1.0f / fmaxf(sqrtf(s0), 1e-8f);
        float rn1 = 1.0f / fmaxf(sqrtf(s1), 1e-8f);
        float rn2 = 1.0f / fmaxf(sqrtf(s2), 1e-8f);
        float rn3 = 1.0f / fmaxf(sqrtf(s3), 1e-8f);

        ACCUM_ROW(g0, v0, rn0);
        ACCUM_ROW(g1, v1, rn1);
        ACCUM_ROW(g2, v2, rn2);
        ACCUM_ROW(g3, v3, rn3);
    }

    // tail (empty for B=1M, NW=8192; kept for generality)
    for (int row = fullIters * NW * 4 + wid; row < B; row += NW) {
        float2 v = feat2[(size_t)row * 64 + lane];
        int g = __builtin_amdgcn_readfirstlane(labels[row] * 4 + sessions[row]);
        float s = fmaf(v.x, v.x, v.y * v.y);
#pragma unroll
        for (int m = 1; m < 64; m <<= 1) s += __shfl_xor(s, m);
        float rn = 1.0f / fmaxf(sqrtf(s), 1e-8f);
        ACCUM_ROW(g, v, rn);
    }

    // per-block LDS reduction: lane owns dims (2*lane, 2*lane+1) -> 2-way bank alias (free)
#pragma unroll
    for (int gg = 0; gg < NGROUPS; ++gg) {
        atomicAdd(&s_all[gg * DIM + lane * 2],            sax[gg]);
        atomicAdd(&s_all[gg * DIM + lane * 2 + 1],        say[gg]);
        atomicAdd(&s_all[1024 + gg * DIM + lane * 2],     wax[gg]);
        atomicAdd(&s_all[1024 + gg * DIM + lane * 2 + 1], way[gg]);
    }
    if (lane == 0) {
#pragma unroll
        for (int gg = 0; gg < NGROUPS; ++gg)
            atomicAdd(&s_all[2048 + gg], (float)scnt[gg]);
    }
    __syncthreads();

    float* rep = gws + (size_t)(blockIdx.x & (NREP - 1)) * WS_FLOATS;
    for (int i = threadIdx.x; i < WS_FLOATS; i += 256) atomicAdd(&rep[i], s_all[i]);
}

__global__ __launch_bounds__(256)
void csca_finalize_kernel(const float* __restrict__ gws, float* __restrict__ out, float invB) {
    __shared__ float red[WS_FLOATS];
    // phase 1: fold the NREP replicas
    for (int i = threadIdx.x; i < WS_FLOATS; i += 256) {
        float s = 0.0f;
#pragma unroll
        for (int r = 0; r < NREP; ++r) s += gws[(size_t)r * WS_FLOATS + i];
        red[i] = s;
    }
    __syncthreads();

    if (threadIdx.x < 64) {
        const int lane = threadIdx.x;
        const float* sums  = red;
        const float* wsums = red + 1024;
        const float* cnts  = red + 2048;
        __shared__ float c_lds[NGROUPS][DIM];
        float cnorm2[NGROUPS];
        float cos_sum = 0.0f;

#pragma unroll
        for (int g = 0; g < NGROUPS; ++g) {
            float invc = 1.0f / cnts[g];
            float c0 = sums[g * DIM + lane] * invc;
            float c1 = sums[g * DIM + 64 + lane] * invc;
            c_lds[g][lane] = c0;
            c_lds[g][64 + lane] = c1;
            float w0 = wsums[g * DIM + lane];
            float w1 = wsums[g * DIM + 64 + lane];
            float pcc = c0 * c0 + c1 * c1;
            float pwc = w0 * c0 + w1 * c1;
#pragma unroll
            for (int m = 1; m < 64; m <<= 1) {
                pcc += __shfl_xor(pcc, m);
                pwc += __shfl_xor(pwc, m);
            }
            cnorm2[g] = pcc;
            cos_sum += pwc / fmaxf(sqrtf(pcc), 1e-8f);
        }
        float center_loss = 1.0f - cos_sum * invB;

        float align = 0.0f;
#pragma unroll
        for (int y = 0; y < 2; ++y) {
            float p0 = 0.0f, p1 = 0.0f;
#pragma unroll
            for (int s = 0; s < 4; ++s) {
                p0 += c_lds[4 * y + s][lane];
                p1 += c_lds[4 * y + s][64 + lane];
            }
            p0 *= 0.25f; p1 *= 0.25f;
            float ppp = p0 * p0 + p1 * p1;
#pragma unroll
            for (int m = 1; m < 64; m <<= 1) ppp += __shfl_xor(ppp, m);
            float pn = fmaxf(sqrtf(ppp), 1e-8f);
            float pc = 0.0f;
#pragma unroll
            for (int s = 0; s < 4; ++s) {
                float d = c_lds[4 * y + s][lane] * p0 + c_lds[4 * y + s][64 + lane] * p1;
#pragma unroll
                for (int m = 1; m < 64; m <<= 1) d += __shfl_xor(d, m);
                float cs = d / (fmaxf(sqrtf(cnorm2[4 * y + s]), 1e-8f) * pn);
                pc += 1.0f - cs;
            }
            align = (align + pc) * 0.25f;  // running /S division, faithful to reference
        }

        if (lane == 0) {
            out[0] = center_loss + align;
            out[1] = center_loss;
            out[2] = align;
        }
    }
}

extern "C" void kernel_launch(void* const* d_in, const int* in_sizes, int n_in,
                              void* d_out, int out_size, void* d_ws, size_t ws_size,
                              hipStream_t stream) {
    const float* feat = (const float*)d_in[0];
    const int* labels = (const int*)d_in[1];
    const int* sessions = (const int*)d_in[2];
    const int B = in_sizes[1];          // 1048576 (features are B x 128)
    float* gws = (float*)d_ws;

    hipMemsetAsync(gws, 0, (size_t)NREP * WS_FLOATS * sizeof(float), stream);

    csca_accum_kernel<<<2048, 256, 0, stream>>>((const float2*)feat, labels, sessions, gws, B);
    csca_finalize_kernel<<<1, 256, 0, stream>>>(gws, (float*)d_out, 1.0f / (float)B);
}

// Round 3
// 203.615 us; speedup vs baseline: 1.3327x; 1.2015x over previous
//
#include <hip/hip_runtime.h>
#include <hip/hip_bf16.h>

#define NGROUPS 8   // L=2 labels * S=4 sessions
#define DIM 128
// per-replica layout (floats): [0,1024) sums[8][128], [1024,2048) wsums[8][128], [2048,2056) counts[8]
#define WS_FLOATS 2056
#define NREP 16     // global atomic replicas to cut same-address chains

// x + dpp(x): one step of a VALU-only wave reduction (no LDS pipe)
template <int CTRL>
__device__ __forceinline__ float dpp_add(float x) {
    int s = __builtin_amdgcn_update_dpp(0, __float_as_int(x), CTRL, 0xF, 0xF, true);
    return x + __int_as_float(s);
}

// full 64-lane sum -> 1/max(sqrt(sum),eps) broadcast as an SGPR float
__device__ __forceinline__ float wave_rnorm(float partial) {
    float r = partial;
    r = dpp_add<0x111>(r);  // row_shr:1
    r = dpp_add<0x112>(r);  // row_shr:2
    r = dpp_add<0x114>(r);  // row_shr:4
    r = dpp_add<0x118>(r);  // row_shr:8
    r = dpp_add<0x142>(r);  // row_bcast:15
    r = dpp_add<0x143>(r);  // row_bcast:31  -> lane 63 holds the total
    float inv = 1.0f / fmaxf(sqrtf(r), 1e-8f);   // only lane 63's value is used
    return __int_as_float(__builtin_amdgcn_readlane(__float_as_int(inv), 63));
}

// accumulate one row; G and RN are wave-uniform (SGPR), so this is a scalar
// branch chain and only the owning group's 4 VALU ops + scalar count execute.
#define ACCUM_ROW(G, V, RN)                                              \
    {                                                                    \
        _Pragma("unroll")                                                \
        for (int gg = 0; gg < NGROUPS; ++gg) {                           \
            if ((G) == gg) {                                             \
                scnt[gg] += 1;                                           \
                sax[gg] += (V).x;                                        \
                say[gg] += (V).y;                                        \
                wax[gg] = fmaf((RN), (V).x, wax[gg]);                    \
                way[gg] = fmaf((RN), (V).y, way[gg]);                    \
            }                                                            \
        }                                                                \
    }

__global__ __launch_bounds__(256, 4)
void csca_accum_kernel(const float2* __restrict__ feat2,
                       const int* __restrict__ labels,
                       const int* __restrict__ sessions,
                       float* __restrict__ gws, int B) {
    __shared__ float s_all[WS_FLOATS];
    for (int i = threadIdx.x; i < WS_FLOATS; i += 256) s_all[i] = 0.0f;
    __syncthreads();

    const int lane = threadIdx.x & 63;
    const int wslot = __builtin_amdgcn_readfirstlane(threadIdx.x >> 6);
    const int wid = blockIdx.x * 4 + wslot;               // wave-uniform (SGPR)
    const int NW = gridDim.x * 4;

    const int4* lab4 = (const int4*)labels;
    const int4* ses4 = (const int4*)sessions;

    float sax[NGROUPS], say[NGROUPS], wax[NGROUPS], way[NGROUPS];
    int scnt[NGROUPS];
#pragma unroll
    for (int g = 0; g < NGROUPS; ++g) {
        sax[g] = 0.0f; say[g] = 0.0f; wax[g] = 0.0f; way[g] = 0.0f; scnt[g] = 0;
    }

    const int fullIters = B / (NW * 4);
    for (int it = 0; it < fullIters; ++it) {
        const int r0 = (it * NW + wid) * 4;               // uniform, %4==0
        // scalar loads of 4 labels + 4 sessions (s_load_dwordx4)
        int4 lb = lab4[r0 >> 2];
        int4 se = ses4[r0 >> 2];
        // 4 coalesced row loads (512B/wave each)
        float2 v0 = feat2[(size_t)(r0 + 0) * 64 + lane];
        float2 v1 = feat2[(size_t)(r0 + 1) * 64 + lane];
        float2 v2 = feat2[(size_t)(r0 + 2) * 64 + lane];
        float2 v3 = feat2[(size_t)(r0 + 3) * 64 + lane];

        float s0 = fmaf(v0.x, v0.x, v0.y * v0.y);
        float s1 = fmaf(v1.x, v1.x, v1.y * v1.y);
        float s2 = fmaf(v2.x, v2.x, v2.y * v2.y);
        float s3 = fmaf(v3.x, v3.x, v3.y * v3.y);
        // 4 independent VALU-only DPP reduce chains (no DS ops) -> SGPR rnorms
        float rn0 = wave_rnorm(s0);
        float rn1 = wave_rnorm(s1);
        float rn2 = wave_rnorm(s2);
        float rn3 = wave_rnorm(s3);

        int g0 = lb.x * 4 + se.x;
        int g1 = lb.y * 4 + se.y;
        int g2 = lb.z * 4 + se.z;
        int g3 = lb.w * 4 + se.w;

        ACCUM_ROW(g0, v0, rn0);
        ACCUM_ROW(g1, v1, rn1);
        ACCUM_ROW(g2, v2, rn2);
        ACCUM_ROW(g3, v3, rn3);
    }

    // tail (empty when B % (NW*4) == 0; kept for generality)
    for (int row = fullIters * NW * 4 + wid; row < B; row += NW) {
        float2 v = feat2[(size_t)row * 64 + lane];
        int g = __builtin_amdgcn_readfirstlane(labels[row] * 4 + sessions[row]);
        float s = fmaf(v.x, v.x, v.y * v.y);
        float rn = wave_rnorm(s);
        ACCUM_ROW(g, v, rn);
    }

    // per-block LDS reduction: lane owns dims (2*lane, 2*lane+1) -> 2-way bank alias (free)
#pragma unroll
    for (int gg = 0; gg < NGROUPS; ++gg) {
        atomicAdd(&s_all[gg * DIM + lane * 2],            sax[gg]);
        atomicAdd(&s_all[gg * DIM + lane * 2 + 1],        say[gg]);
        atomicAdd(&s_all[1024 + gg * DIM + lane * 2],     wax[gg]);
        atomicAdd(&s_all[1024 + gg * DIM + lane * 2 + 1], way[gg]);
    }
    if (lane == 0) {
#pragma unroll
        for (int gg = 0; gg < NGROUPS; ++gg)
            atomicAdd(&s_all[2048 + gg], (float)scnt[gg]);
    }
    __syncthreads();

    float* rep = gws + (size_t)(blockIdx.x & (NREP - 1)) * WS_FLOATS;
    for (int i = threadIdx.x; i < WS_FLOATS; i += 256) atomicAdd(&rep[i], s_all[i]);
}

__global__ __launch_bounds__(256)
void csca_finalize_kernel(const float* __restrict__ gws, float* __restrict__ out, float invB) {
    __shared__ float red[WS_FLOATS];
    for (int i = threadIdx.x; i < WS_FLOATS; i += 256) {
        float s = 0.0f;
#pragma unroll
        for (int r = 0; r < NREP; ++r) s += gws[(size_t)r * WS_FLOATS + i];
        red[i] = s;
    }
    __syncthreads();

    if (threadIdx.x < 64) {
        const int lane = threadIdx.x;
        const float* sums  = red;
        const float* wsums = red + 1024;
        const float* cnts  = red + 2048;
        __shared__ float c_lds[NGROUPS][DIM];
        float cnorm2[NGROUPS];
        float cos_sum = 0.0f;

#pragma unroll
        for (int g = 0; g < NGROUPS; ++g) {
            float invc = 1.0f / cnts[g];
            float c0 = sums[g * DIM + lane] * invc;
            float c1 = sums[g * DIM + 64 + lane] * invc;
            c_lds[g][lane] = c0;
            c_lds[g][64 + lane] = c1;
            float w0 = wsums[g * DIM + lane];
            float w1 = wsums[g * DIM + 64 + lane];
            float pcc = c0 * c0 + c1 * c1;
            float pwc = w0 * c0 + w1 * c1;
#pragma unroll
            for (int m = 1; m < 64; m <<= 1) {
                pcc += __shfl_xor(pcc, m);
                pwc += __shfl_xor(pwc, m);
            }
            cnorm2[g] = pcc;
            cos_sum += pwc / fmaxf(sqrtf(pcc), 1e-8f);
        }
        float center_loss = 1.0f - cos_sum * invB;

        float align = 0.0f;
#pragma unroll
        for (int y = 0; y < 2; ++y) {
            float p0 = 0.0f, p1 = 0.0f;
#pragma unroll
            for (int s = 0; s < 4; ++s) {
                p0 += c_lds[4 * y + s][lane];
                p1 += c_lds[4 * y + s][64 + lane];
            }
            p0 *= 0.25f; p1 *= 0.25f;
            float ppp = p0 * p0 + p1 * p1;
#pragma unroll
            for (int m = 1; m < 64; m <<= 1) ppp += __shfl_xor(ppp, m);
            float pn = fmaxf(sqrtf(ppp), 1e-8f);
            float pc = 0.0f;
#pragma unroll
            for (int s = 0; s < 4; ++s) {
                float d = c_lds[4 * y + s][lane] * p0 + c_lds[4 * y + s][64 + lane] * p1;
#pragma unroll
                for (int m = 1; m < 64; m <<= 1) d += __shfl_xor(d, m);
                float cs = d / (fmaxf(sqrtf(cnorm2[4 * y + s]), 1e-8f) * pn);
                pc += 1.0f - cs;
            }
            align = (align + pc) * 0.25f;  // running /S division, faithful to reference
        }

        if (lane == 0) {
            out[0] = center_loss + align;
            out[1] = center_loss;
            out[2] = align;
        }
    }
}

extern "C" void kernel_launch(void* const* d_in, const int* in_sizes, int n_in,
                              void* d_out, int out_size, void* d_ws, size_t ws_size,
                              hipStream_t stream) {
    const float* feat = (const float*)d_in[0];
    const int* labels = (const int*)d_in[1];
    const int* sessions = (const int*)d_in[2];
    const int B = in_sizes[1];          // 1048576 (features are B x 128)
    float* gws = (float*)d_ws;

    hipMemsetAsync(gws, 0, (size_t)NREP * WS_FLOATS * sizeof(float), stream);

    csca_accum_kernel<<<2048, 256, 0, stream>>>((const float2*)feat, labels, sessions, gws, B);
    csca_finalize_kernel<<<1, 256, 0, stream>>>(gws, (float*)d_out, 1.0f / (float)B);
}

// Round 4
// 197.897 us; speedup vs baseline: 1.3712x; 1.0289x over previous
//
#include <hip/hip_runtime.h>
#include <hip/hip_bf16.h>

#define NGROUPS 8   // L=2 labels * S=4 sessions
#define DIM 128
// per-replica layout (floats): [0,1024) sums[8][128], [1024,2048) wsums[8][128], [2048,2056) counts[8]
#define WS_FLOATS 2056
#define NREP 16     // global atomic replicas to cut same-address chains

typedef float f32x4 __attribute__((ext_vector_type(4)));

// x + dpp(x): one step of a VALU-only wave reduction (no LDS pipe)
template <int CTRL>
__device__ __forceinline__ float dpp_add(float x) {
    int s = __builtin_amdgcn_update_dpp(0, __float_as_int(x), CTRL, 0xF, 0xF, true);
    return x + __int_as_float(s);
}

// per-32-lane-half sums: after shr1/2/4/8 + bcast15, lane31 = sum(lanes 0..31),
// lane63 = sum(lanes 32..63). Returns {1/max(sqrt(sumLo),eps), same for Hi} as SGPRs.
__device__ __forceinline__ float2 pair_rnorm(float ss) {
    float r = ss;
    r = dpp_add<0x111>(r);  // row_shr:1
    r = dpp_add<0x112>(r);  // row_shr:2
    r = dpp_add<0x114>(r);  // row_shr:4
    r = dpp_add<0x118>(r);  // row_shr:8
    r = dpp_add<0x142>(r);  // row_bcast:15
    float inv = 1.0f / fmaxf(sqrtf(r), 1e-8f);  // valid at lanes 31 and 63
    float a = __int_as_float(__builtin_amdgcn_readlane(__float_as_int(inv), 31));
    float b = __int_as_float(__builtin_amdgcn_readlane(__float_as_int(inv), 63));
    return make_float2(a, b);
}

// G and RN wave-uniform -> scalar branch chain; only owning group's 8 VALU run.
#define ACCUM_HALF(G, V, RN)                                             \
    {                                                                    \
        _Pragma("unroll")                                                \
        for (int gg = 0; gg < NGROUPS; ++gg) {                           \
            if ((G) == gg) {                                             \
                cnt[gg] += 1;                                            \
                sa[gg][0] += (V).x; sa[gg][1] += (V).y;                  \
                sa[gg][2] += (V).z; sa[gg][3] += (V).w;                  \
                wa[gg][0] = fmaf((RN), (V).x, wa[gg][0]);                \
                wa[gg][1] = fmaf((RN), (V).y, wa[gg][1]);                \
                wa[gg][2] = fmaf((RN), (V).z, wa[gg][2]);                \
                wa[gg][3] = fmaf((RN), (V).w, wa[gg][3]);                \
            }                                                            \
        }                                                                \
    }

__global__ __launch_bounds__(256, 4)
void csca_accum_kernel(const f32x4* __restrict__ feat4,
                       const int* __restrict__ labels,
                       const int* __restrict__ sessions,
                       float* __restrict__ gws, int B) {
    __shared__ float s_all[WS_FLOATS];
    for (int i = threadIdx.x; i < WS_FLOATS; i += 256) s_all[i] = 0.0f;
    __syncthreads();

    const int lane = threadIdx.x & 63;
    const int wslot = __builtin_amdgcn_readfirstlane(threadIdx.x >> 6);
    const int wid = blockIdx.x * 4 + wslot;               // wave-uniform (SGPR)
    const int NW = gridDim.x * 4;
    const bool lo = lane < 32;
    const f32x4 zz = {0.0f, 0.0f, 0.0f, 0.0f};

    const int4* lab4 = (const int4*)labels;
    const int4* ses4 = (const int4*)sessions;

    float sa[NGROUPS][4], wa[NGROUPS][4];
    int cnt[NGROUPS];
#pragma unroll
    for (int g = 0; g < NGROUPS; ++g) {
        cnt[g] = 0;
#pragma unroll
        for (int k = 0; k < 4; ++k) { sa[g][k] = 0.0f; wa[g][k] = 0.0f; }
    }

    const int fullIters = B / (NW * 4);
    if (fullIters > 0) {
        // prologue: load tile 0 (rows r0..r0+3; one f32x4 wave-load = 2 rows)
        int r0 = wid * 4;
        f32x4 v01 = feat4[(size_t)r0 * 32 + lane];
        f32x4 v23 = feat4[(size_t)r0 * 32 + 64 + lane];
        int4 lb = lab4[r0 >> 2];
        int4 se = ses4[r0 >> 2];

        for (int it = 0; it < fullIters; ++it) {
            // prefetch next tile while computing current (2-deep pipeline)
            const int itn = (it + 1 < fullIters) ? (it + 1) : it;
            const int r0n = (itn * NW + wid) * 4;
            f32x4 n01 = feat4[(size_t)r0n * 32 + lane];
            f32x4 n23 = feat4[(size_t)r0n * 32 + 64 + lane];
            int4 nlb = lab4[r0n >> 2];
            int4 nse = ses4[r0n >> 2];

            float ss01 = v01.x * v01.x + v01.y * v01.y + v01.z * v01.z + v01.w * v01.w;
            float ss23 = v23.x * v23.x + v23.y * v23.y + v23.z * v23.z + v23.w * v23.w;
            float2 rn01 = pair_rnorm(ss01);
            float2 rn23 = pair_rnorm(ss23);

            int g0 = lb.x * 4 + se.x;
            int g1 = lb.y * 4 + se.y;
            int g2 = lb.z * 4 + se.z;
            int g3 = lb.w * 4 + se.w;

            f32x4 ha, hb;
            ha = lo ? v01 : zz;
            hb = lo ? zz : v01;
            ACCUM_HALF(g0, ha, rn01.x);
            ACCUM_HALF(g1, hb, rn01.y);
            ha = lo ? v23 : zz;
            hb = lo ? zz : v23;
            ACCUM_HALF(g2, ha, rn23.x);
            ACCUM_HALF(g3, hb, rn23.y);

            v01 = n01; v23 = n23; lb = nlb; se = nse;
        }
    }

    // tail (empty when B % (NW*4) == 0; kept for generality)
    for (int row = fullIters * NW * 4 + wid; row < B; row += NW) {
        f32x4 v = zz;
        if (lo) v = feat4[(size_t)row * 32 + lane];
        int g = __builtin_amdgcn_readfirstlane(labels[row] * 4 + sessions[row]);
        float ss = v.x * v.x + v.y * v.y + v.z * v.z + v.w * v.w;
        float2 rn = pair_rnorm(ss);
        ACCUM_HALF(g, v, rn.x);   // upper lanes hold zeros: harmless
    }

    // fold the two wave halves: lane l (<32) ends with dims [4l,4l+3] totals
#pragma unroll
    for (int gg = 0; gg < NGROUPS; ++gg) {
#pragma unroll
        for (int k = 0; k < 4; ++k) {
            sa[gg][k] += __shfl_xor(sa[gg][k], 32);
            wa[gg][k] += __shfl_xor(wa[gg][k], 32);
        }
    }
    if (lo) {
#pragma unroll
        for (int gg = 0; gg < NGROUPS; ++gg) {
#pragma unroll
            for (int k = 0; k < 4; ++k) {
                atomicAdd(&s_all[gg * DIM + lane * 4 + k], sa[gg][k]);
                atomicAdd(&s_all[1024 + gg * DIM + lane * 4 + k], wa[gg][k]);
            }
        }
    }
    if (lane == 0) {
#pragma unroll
        for (int gg = 0; gg < NGROUPS; ++gg)
            atomicAdd(&s_all[2048 + gg], (float)cnt[gg]);
    }
    __syncthreads();

    float* rep = gws + (size_t)(blockIdx.x & (NREP - 1)) * WS_FLOATS;
    for (int i = threadIdx.x; i < WS_FLOATS; i += 256) atomicAdd(&rep[i], s_all[i]);
}

__global__ __launch_bounds__(256)
void csca_finalize_kernel(const float* __restrict__ gws, float* __restrict__ out, float invB) {
    __shared__ float red[WS_FLOATS];
    for (int i = threadIdx.x; i < WS_FLOATS; i += 256) {
        float s = 0.0f;
#pragma unroll
        for (int r = 0; r < NREP; ++r) s += gws[(size_t)r * WS_FLOATS + i];
        red[i] = s;
    }
    __syncthreads();

    if (threadIdx.x < 64) {
        const int lane = threadIdx.x;
        const float* sums  = red;
        const float* wsums = red + 1024;
        const float* cnts  = red + 2048;
        __shared__ float c_lds[NGROUPS][DIM];
        float cnorm2[NGROUPS];
        float cos_sum = 0.0f;

#pragma unroll
        for (int g = 0; g < NGROUPS; ++g) {
            float invc = 1.0f / cnts[g];
            float c0 = sums[g * DIM + lane] * invc;
            float c1 = sums[g * DIM + 64 + lane] * invc;
            c_lds[g][lane] = c0;
            c_lds[g][64 + lane] = c1;
            float w0 = wsums[g * DIM + lane];
            float w1 = wsums[g * DIM + 64 + lane];
            float pcc = c0 * c0 + c1 * c1;
            float pwc = w0 * c0 + w1 * c1;
#pragma unroll
            for (int m = 1; m < 64; m <<= 1) {
                pcc += __shfl_xor(pcc, m);
                pwc += __shfl_xor(pwc, m);
            }
            cnorm2[g] = pcc;
            cos_sum += pwc / fmaxf(sqrtf(pcc), 1e-8f);
        }
        float center_loss = 1.0f - cos_sum * invB;

        float align = 0.0f;
#pragma unroll
        for (int y = 0; y < 2; ++y) {
            float p0 = 0.0f, p1 = 0.0f;
#pragma unroll
            for (int s = 0; s < 4; ++s) {
                p0 += c_lds[4 * y + s][lane];
                p1 += c_lds[4 * y + s][64 + lane];
            }
            p0 *= 0.25f; p1 *= 0.25f;
            float ppp = p0 * p0 + p1 * p1;
#pragma unroll
            for (int m = 1; m < 64; m <<= 1) ppp += __shfl_xor(ppp, m);
            float pn = fmaxf(sqrtf(ppp), 1e-8f);
            float pc = 0.0f;
#pragma unroll
            for (int s = 0; s < 4; ++s) {
                float d = c_lds[4 * y + s][lane] * p0 + c_lds[4 * y + s][64 + lane] * p1;
#pragma unroll
                for (int m = 1; m < 64; m <<= 1) d += __shfl_xor(d, m);
                float cs = d / (fmaxf(sqrtf(cnorm2[4 * y + s]), 1e-8f) * pn);
                pc += 1.0f - cs;
            }
            align = (align + pc) * 0.25f;  // running /S division, faithful to reference
        }

        if (lane == 0) {
            out[0] = center_loss + align;
            out[1] = center_loss;
            out[2] = align;
        }
    }
}

extern "C" void kernel_launch(void* const* d_in, const int* in_sizes, int n_in,
                              void* d_out, int out_size, void* d_ws, size_t ws_size,
                              hipStream_t stream) {
    const float* feat = (const float*)d_in[0];
    const int* labels = (const int*)d_in[1];
    const int* sessions = (const int*)d_in[2];
    const int B = in_sizes[1];          // 1048576 (features are B x 128)
    float* gws = (float*)d_ws;

    hipMemsetAsync(gws, 0, (size_t)NREP * WS_FLOATS * sizeof(float), stream);

    csca_accum_kernel<<<2048, 256, 0, stream>>>((const f32x4*)feat, labels, sessions, gws, B);
    csca_finalize_kernel<<<1, 256, 0, stream>>>(gws, (float*)d_out, 1.0f / (float)B);
}